// Round 8
// baseline (74.993 us; speedup 1.0000x reference)
//
#include <hip/hip_runtime.h>

#define FDIM   251
#define NFILT  80
#define KPAD   256        // K padded to 8 chunks of 32 (zeros past 250)
#define T_IN   64000
#define T_OUT  63750      // 64000 - 251 + 1
#define NCHUNK 1024       // output positions per block; wave owns contiguous 256
#define NFT    5          // filter tiles (16 filters each)
#define CPYLEN 648        // dwords per shifted copy; 648 % 32 == 8 -> bank stagger
#define XSTOT  (8 * CPYLEN)

typedef short bf16x8 __attribute__((ext_vector_type(8)));
typedef float f32x4  __attribute__((ext_vector_type(4)));

__device__ __forceinline__ unsigned short f2bf(float f) {
  unsigned int u = __float_as_uint(f);
  unsigned int r = (u + 0x7fffu + ((u >> 16) & 1u)) >> 16;   // RNE
  return (unsigned short)r;
}
__device__ __forceinline__ unsigned int packbf(float a, float b) {
  return (unsigned int)f2bf(a) | ((unsigned int)f2bf(b) << 16);
}

// ---------------------------------------------------------------------------
// Filter construction (validated rounds 1-7). Emits bf16 W[80][256].
// ---------------------------------------------------------------------------
__device__ __forceinline__ void norm_pm1_shared(float* a, float* scratch, int tid) {
  float v  = (tid < FDIM) ? a[tid] : 0.f;
  float mn = (tid < FDIM) ? v : 1e30f;
  float mx = (tid < FDIM) ? v : -1e30f;
  #pragma unroll
  for (int o = 32; o > 0; o >>= 1) {
    mn = fminf(mn, __shfl_down(mn, o));
    mx = fmaxf(mx, __shfl_down(mx, o));
  }
  const int wid = tid >> 6;
  if ((tid & 63) == 0) { scratch[wid] = mn; scratch[4 + wid] = mx; }
  __syncthreads();
  if (tid == 0) {
    scratch[0] = fminf(fminf(scratch[0], scratch[1]), fminf(scratch[2], scratch[3]));
    scratch[4] = fmaxf(fmaxf(scratch[4], scratch[5]), fmaxf(scratch[6], scratch[7]));
  }
  __syncthreads();
  const float gmn = scratch[0], gmx = scratch[4];
  const float nv = 2.f * (v - gmn) / (gmx - gmn + 1e-6f) - 1.f;
  __syncthreads();
  float s = (tid < FDIM) ? nv : 0.f;
  #pragma unroll
  for (int o = 32; o > 0; o >>= 1) s += __shfl_down(s, o);
  if ((tid & 63) == 0) scratch[wid] = s;
  __syncthreads();
  if (tid == 0) scratch[0] = (scratch[0] + scratch[1] + scratch[2] + scratch[3]) / 251.f;
  __syncthreads();
  const float mean = scratch[0];
  if (tid < FDIM) a[tid] = nv - mean;
  __syncthreads();
}

__global__ __launch_bounds__(256) void build_filters_kernel(
    const float* __restrict__ nf1, const float* __restrict__ nf2,
    const float* __restrict__ nf3, const float* __restrict__ nf4,
    const float* __restrict__ amp1, const float* __restrict__ amp2,
    unsigned short* __restrict__ Wbf) {
  __shared__ float ir1[FDIM], ir2[FDIM], casc[FDIM];
  __shared__ float scratch[8];
  const int f = blockIdx.x, tid = threadIdx.x;
  const float FS  = 16000.f;
  const float MF  = 50.f / 16000.f;
  const float PIF = 3.14159265358979323846f;
  const float TPI = 6.28318530717958647692f;

  const float f1 = fminf(fmaxf(fabsf(nf1[f]) + MF, 0.f), 0.5f);
  const float f2 = fminf(fmaxf(f1 + fabsf(nf2[f] - f1) + MF, 0.f), 0.5f);
  const float f3 = fminf(fmaxf(fabsf(nf3[f]) + MF, 0.f), 0.5f);
  const float f4 = fminf(fmaxf(f3 + fabsf(nf4[f] - f3) + MF, 0.f), 0.5f);
  const float a1 = fabsf(amp1[f]);
  const float a2 = fabsf(amp2[f]);

  if (tid < FDIM) {
    const float t = (float)(tid + 1) / FS;
    {
      const float fcs = 0.5f * (f1 + f2) * FS, bws = (f2 - f1) * FS;
      const float pb = PIF * bws;
      ir1[tid] = a1 * expf(-2.f * pb * pb * (t * t)) * cosf(TPI * fcs * t);
    }
    {
      const float fcs = 0.5f * (f3 + f4) * FS, bws = (f4 - f3) * FS;
      const float pb = PIF * bws;
      ir2[tid] = a2 * expf(-2.f * pb * pb * (t * t)) * cosf(TPI * fcs * t);
    }
  }
  __syncthreads();
  norm_pm1_shared(ir1, scratch, tid);
  norm_pm1_shared(ir2, scratch, tid);

  if (tid < FDIM) {
    const int i = tid;
    const int plo = (i - 125 > 0) ? (i - 125) : 0;
    const int phi = (i + 125 < 250) ? (i + 125) : 250;
    float s = 0.f;
    for (int p = plo; p <= phi; ++p) s += ir1[p] * ir2[p + 125 - i];
    casc[i] = s;
  }
  __syncthreads();
  norm_pm1_shared(casc, scratch, tid);

  if (tid < KPAD) {
    float v = 0.f;
    if (tid < FDIM) {
      const float win = 0.54f - 0.46f * cosf(TPI * ((float)tid / 250.f));
      v = casc[tid] * win;
    }
    Wbf[(size_t)f * KPAD + tid] = f2bf(v);
  }
}

// ---------------------------------------------------------------------------
// Implicit-GEMM conv with register-resident sliding fragment window.
// Block = 16 filters x 1024 t, 4 waves; wave owns contiguous 256 t.
// Key identity: B-fragment(tile j, chunk c) = G[j + 2c] where G[p] is the
// 8-elem x window starting at tw0 + 16p + m + 8h. Same-parity tiles share
// 7/8 fragments -> two parity passes, each with an 8-fragment register ring:
//   invariant before tile tj: slot s holds E[s'], s' = s (mod 8), s' in [tj, tj+8)
//   tile tj: 8 MFMA on slots (tj+c)&7, store, then one new fragment load.
// LDS reads/wave: 30 (vs 128 in round 7). All ring indices static (full
// unroll) -> stays in registers (~90 VGPR; round-6 spill lesson respected).
// ---------------------------------------------------------------------------
__global__ __launch_bounds__(256, 4) void conv_mfma_kernel(
    const float* __restrict__ xin, const unsigned short* __restrict__ Wbf,
    float* __restrict__ outp) {
  __shared__ __align__(16) unsigned int xs[XSTOT];
  const int tid = threadIdx.x;
  const int n0  = blockIdx.x * NCHUNK;
  const int ft  = blockIdx.y;
  const int b   = blockIdx.z;
  const int l   = tid & 63, w = tid >> 6;
  const int m   = l & 15, h = l >> 4;

  // ---- stage x as 8 shifted bf16-pair copies: C_j[i] = (x[2i+j], x[2i+j+1]) ----
  const float* xg = xin + (size_t)b * T_IN;
  for (int i = tid; i < CPYLEN - 4; i += 256) {
    float e[10];
    #pragma unroll
    for (int q = 0; q < 10; ++q) {
      const int g = n0 + 2 * i + q;
      e[q] = (g < T_IN) ? xg[g] : 0.f;
    }
    #pragma unroll
    for (int j = 0; j < 8; ++j)
      xs[j * CPYLEN + i] = packbf(e[j], e[j + 1]);
  }

  // ---- W fragments (A-operand) for this 16-filter tile: row = m ----
  const short* Wp = (const short*)Wbf;
  bf16x8 afr[8];
  #pragma unroll
  for (int c = 0; c < 8; ++c)
    afr[c] = *(const bf16x8*)(Wp + (ft * 16 + m) * KPAD + c * 32 + h * 8);

  __syncthreads();

  // lane-constant fragment addressing (validated r4-r7):
  // G[p] -> copy m&7, 16B-unit index qbase + 2p, qbase = tw0/8 + h + (m>>3)
  const unsigned int* psrc = xs + (m & 7) * CPYLEN;
  const int tw0 = w * 256;
  const int qbase = (tw0 >> 3) + h + (m >> 3);
  const size_t rowh = ((size_t)b * NFILT + ft * 16 + 4 * h) * T_OUT;

  #pragma unroll
  for (int P = 0; P < 2; ++P) {                 // parity pass: tiles j = P + 2*tj
    const unsigned int* dbase = psrc + 4 * qbase + 8 * P;  // frag s at +16*s dwords

    bf16x8 E[8];
    #pragma unroll
    for (int s = 0; s < 8; ++s)
      E[s] = *(const bf16x8*)(dbase + 16 * s);

    #pragma unroll
    for (int tj = 0; tj < 8; ++tj) {
      f32x4 acc = (f32x4){0.f, 0.f, 0.f, 0.f};
      #pragma unroll
      for (int c = 0; c < 8; ++c)
        acc = __builtin_amdgcn_mfma_f32_16x16x32_bf16(afr[c], E[(tj + c) & 7], acc, 0, 0, 0);

      const int tg = n0 + tw0 + 16 * P + 32 * tj + m;   // D col = m
      if (tg < T_OUT) {
        #pragma unroll
        for (int r = 0; r < 4; ++r)                     // D row = 4h + r
          outp[rowh + (size_t)r * T_OUT + tg] = acc[r];
      }

      if (tj < 7)                                       // slide: E[tj+8] -> slot tj&7
        E[tj & 7] = *(const bf16x8*)(dbase + 16 * (tj + 8));
    }
  }
}

// ---------------------------------------------------------------------------
extern "C" void kernel_launch(void* const* d_in, const int* in_sizes, int n_in,
                              void* d_out, int out_size, void* d_ws, size_t ws_size,
                              hipStream_t stream) {
  const float* x    = (const float*)d_in[0];
  const float* nf1  = (const float*)d_in[1];
  const float* nf2  = (const float*)d_in[2];
  const float* nf3  = (const float*)d_in[3];
  const float* nf4  = (const float*)d_in[4];
  const float* amp1 = (const float*)d_in[5];
  const float* amp2 = (const float*)d_in[6];
  unsigned short* Wbf = (unsigned short*)d_ws;   // 80*256*2 = 40 KB scratch
  float* out = (float*)d_out;

  build_filters_kernel<<<NFILT, 256, 0, stream>>>(nf1, nf2, nf3, nf4, amp1, amp2, Wbf);

  dim3 grid((T_OUT + NCHUNK - 1) / NCHUNK, NFT, 8);   // 63 x 5 x 8
  conv_mfma_kernel<<<grid, 256, 0, stream>>>(x, Wbf, out);
}

// Round 9
// 74.024 us; speedup vs baseline: 1.0131x; 1.0131x over previous
//
#include <hip/hip_runtime.h>

#define FDIM   251
#define NFILT  80
#define KPAD   256        // K padded to 8 chunks of 32 (zeros past 250)
#define T_IN   64000
#define T_OUT  63750      // 64000 - 251 + 1
#define NCHUNK 1024       // output positions per block; wave owns contiguous 256
#define NFT    5          // filter tiles (16 filters each)
#define CPYLEN 648        // dwords per shifted copy; 648 % 32 == 8 -> bank stagger
#define XSTOT  (8 * CPYLEN)

typedef short bf16x8 __attribute__((ext_vector_type(8)));
typedef float f32x4  __attribute__((ext_vector_type(4)));

__device__ __forceinline__ unsigned short f2bf(float f) {
  unsigned int u = __float_as_uint(f);
  unsigned int r = (u + 0x7fffu + ((u >> 16) & 1u)) >> 16;   // RNE
  return (unsigned short)r;
}
__device__ __forceinline__ unsigned int packbf(float a, float b) {
  return (unsigned int)f2bf(a) | ((unsigned int)f2bf(b) << 16);
}

// ---------------------------------------------------------------------------
// Filter construction (validated rounds 1-8). Emits bf16 W[80][256].
// ---------------------------------------------------------------------------
__device__ __forceinline__ void norm_pm1_shared(float* a, float* scratch, int tid) {
  float v  = (tid < FDIM) ? a[tid] : 0.f;
  float mn = (tid < FDIM) ? v : 1e30f;
  float mx = (tid < FDIM) ? v : -1e30f;
  #pragma unroll
  for (int o = 32; o > 0; o >>= 1) {
    mn = fminf(mn, __shfl_down(mn, o));
    mx = fmaxf(mx, __shfl_down(mx, o));
  }
  const int wid = tid >> 6;
  if ((tid & 63) == 0) { scratch[wid] = mn; scratch[4 + wid] = mx; }
  __syncthreads();
  if (tid == 0) {
    scratch[0] = fminf(fminf(scratch[0], scratch[1]), fminf(scratch[2], scratch[3]));
    scratch[4] = fmaxf(fmaxf(scratch[4], scratch[5]), fmaxf(scratch[6], scratch[7]));
  }
  __syncthreads();
  const float gmn = scratch[0], gmx = scratch[4];
  const float nv = 2.f * (v - gmn) / (gmx - gmn + 1e-6f) - 1.f;
  __syncthreads();
  float s = (tid < FDIM) ? nv : 0.f;
  #pragma unroll
  for (int o = 32; o > 0; o >>= 1) s += __shfl_down(s, o);
  if ((tid & 63) == 0) scratch[wid] = s;
  __syncthreads();
  if (tid == 0) scratch[0] = (scratch[0] + scratch[1] + scratch[2] + scratch[3]) / 251.f;
  __syncthreads();
  const float mean = scratch[0];
  if (tid < FDIM) a[tid] = nv - mean;
  __syncthreads();
}

__global__ __launch_bounds__(256) void build_filters_kernel(
    const float* __restrict__ nf1, const float* __restrict__ nf2,
    const float* __restrict__ nf3, const float* __restrict__ nf4,
    const float* __restrict__ amp1, const float* __restrict__ amp2,
    unsigned short* __restrict__ Wbf) {
  __shared__ float ir1[FDIM], ir2[FDIM], casc[FDIM];
  __shared__ float scratch[8];
  const int f = blockIdx.x, tid = threadIdx.x;
  const float FS  = 16000.f;
  const float MF  = 50.f / 16000.f;
  const float PIF = 3.14159265358979323846f;
  const float TPI = 6.28318530717958647692f;

  const float f1 = fminf(fmaxf(fabsf(nf1[f]) + MF, 0.f), 0.5f);
  const float f2 = fminf(fmaxf(f1 + fabsf(nf2[f] - f1) + MF, 0.f), 0.5f);
  const float f3 = fminf(fmaxf(fabsf(nf3[f]) + MF, 0.f), 0.5f);
  const float f4 = fminf(fmaxf(f3 + fabsf(nf4[f] - f3) + MF, 0.f), 0.5f);
  const float a1 = fabsf(amp1[f]);
  const float a2 = fabsf(amp2[f]);

  if (tid < FDIM) {
    const float t = (float)(tid + 1) / FS;
    {
      const float fcs = 0.5f * (f1 + f2) * FS, bws = (f2 - f1) * FS;
      const float pb = PIF * bws;
      ir1[tid] = a1 * expf(-2.f * pb * pb * (t * t)) * cosf(TPI * fcs * t);
    }
    {
      const float fcs = 0.5f * (f3 + f4) * FS, bws = (f4 - f3) * FS;
      const float pb = PIF * bws;
      ir2[tid] = a2 * expf(-2.f * pb * pb * (t * t)) * cosf(TPI * fcs * t);
    }
  }
  __syncthreads();
  norm_pm1_shared(ir1, scratch, tid);
  norm_pm1_shared(ir2, scratch, tid);

  if (tid < FDIM) {
    const int i = tid;
    const int plo = (i - 125 > 0) ? (i - 125) : 0;
    const int phi = (i + 125 < 250) ? (i + 125) : 250;
    float s = 0.f;
    for (int p = plo; p <= phi; ++p) s += ir1[p] * ir2[p + 125 - i];
    casc[i] = s;
  }
  __syncthreads();
  norm_pm1_shared(casc, scratch, tid);

  if (tid < KPAD) {
    float v = 0.f;
    if (tid < FDIM) {
      const float win = 0.54f - 0.46f * cosf(TPI * ((float)tid / 250.f));
      v = casc[tid] * win;
    }
    Wbf[(size_t)f * KPAD + tid] = f2bf(v);
  }
}

// ---------------------------------------------------------------------------
// Implicit-GEMM conv = round-7 compute (2-chain MFMA interleave, validated
// addressing) + BURST STORE epilogue. Wave accumulates a half-pass of 8
// tiles (128 t x 16 f) in registers (acc[8] = 32 VGPR; r6's 16-acc spill
// avoided), then bursts 8 back-to-back store instrs per row-quad:
// 512 B contiguous per f-row per burst episode (4x round 7's 128 B).
// Theory: ~16k concurrent 128B write frontiers >> ~4k HBM banks = page
// thrash; larger per-episode bursts cut page activations ~4x.
// ---------------------------------------------------------------------------
__global__ __launch_bounds__(256, 4) void conv_mfma_kernel(
    const float* __restrict__ xin, const unsigned short* __restrict__ Wbf,
    float* __restrict__ outp) {
  __shared__ __align__(16) unsigned int xs[XSTOT];
  const int tid = threadIdx.x;
  const int n0  = blockIdx.x * NCHUNK;
  const int ft  = blockIdx.y;
  const int b   = blockIdx.z;
  const int l   = tid & 63, w = tid >> 6;
  const int m   = l & 15, h = l >> 4;

  // ---- stage x as 8 shifted bf16-pair copies: C_j[i] = (x[2i+j], x[2i+j+1]) ----
  const float* xg = xin + (size_t)b * T_IN;
  for (int i = tid; i < CPYLEN - 4; i += 256) {
    float e[10];
    #pragma unroll
    for (int q = 0; q < 10; ++q) {
      const int g = n0 + 2 * i + q;
      e[q] = (g < T_IN) ? xg[g] : 0.f;
    }
    #pragma unroll
    for (int j = 0; j < 8; ++j)
      xs[j * CPYLEN + i] = packbf(e[j], e[j + 1]);
  }

  // ---- W fragments (A-operand) for this 16-filter tile: row = m ----
  const short* Wp = (const short*)Wbf;
  bf16x8 afr[8];
  #pragma unroll
  for (int c = 0; c < 8; ++c)
    afr[c] = *(const bf16x8*)(Wp + (ft * 16 + m) * KPAD + c * 32 + h * 8);

  __syncthreads();

  // lane-constant fragment addressing (validated r4-r8):
  // tile j, chunk c -> copy m&7, 16B-unit index tw0/8 + 2j + lane_q + 4c
  const unsigned int* psrc = xs + (m & 7) * CPYLEN;
  const int lane_q = h + (m >> 3);
  const int tw0 = w * 256;
  const size_t rowh = ((size_t)b * NFILT + ft * 16 + 4 * h) * T_OUT;

  #pragma unroll
  for (int hp = 0; hp < 2; ++hp) {             // half-pass: tiles 8*hp .. 8*hp+7
    f32x4 acc[8];
    #pragma unroll
    for (int j = 0; j < 8; ++j) acc[j] = (f32x4){0.f, 0.f, 0.f, 0.f};

    #pragma unroll
    for (int jp = 0; jp < 4; ++jp) {           // pairs of tiles, 2 chains for ILP
      const int qA = (tw0 >> 3) + 2 * (8 * hp + 2 * jp) + lane_q;
      #pragma unroll
      for (int c = 0; c < 8; ++c) {
        const bf16x8 xa = *(const bf16x8*)(psrc + 4 * (qA + 4 * c));
        const bf16x8 xb = *(const bf16x8*)(psrc + 4 * (qA + 2 + 4 * c));
        acc[2 * jp]     = __builtin_amdgcn_mfma_f32_16x16x32_bf16(afr[c], xa, acc[2 * jp],     0, 0, 0);
        acc[2 * jp + 1] = __builtin_amdgcn_mfma_f32_16x16x32_bf16(afr[c], xb, acc[2 * jp + 1], 0, 0, 0);
      }
    }

    // ---- burst store: per (h,r) row, 8 back-to-back 64B pieces = 512 B ----
    const int tb = n0 + tw0 + hp * 128 + m;    // D col = m
    #pragma unroll
    for (int r = 0; r < 4; ++r) {              // D row = 4h + r
      const size_t rb = rowh + (size_t)r * T_OUT;
      #pragma unroll
      for (int j = 0; j < 8; ++j) {
        const int tg = tb + 16 * j;
        if (tg < T_OUT) outp[rb + tg] = acc[j][r];
      }
    }
  }
}

// ---------------------------------------------------------------------------
extern "C" void kernel_launch(void* const* d_in, const int* in_sizes, int n_in,
                              void* d_out, int out_size, void* d_ws, size_t ws_size,
                              hipStream_t stream) {
  const float* x    = (const float*)d_in[0];
  const float* nf1  = (const float*)d_in[1];
  const float* nf2  = (const float*)d_in[2];
  const float* nf3  = (const float*)d_in[3];
  const float* nf4  = (const float*)d_in[4];
  const float* amp1 = (const float*)d_in[5];
  const float* amp2 = (const float*)d_in[6];
  unsigned short* Wbf = (unsigned short*)d_ws;   // 80*256*2 = 40 KB scratch
  float* out = (float*)d_out;

  build_filters_kernel<<<NFILT, 256, 0, stream>>>(nf1, nf2, nf3, nf4, amp1, amp2, Wbf);

  dim3 grid((T_OUT + NCHUNK - 1) / NCHUNK, NFT, 8);   // 63 x 5 x 8
  conv_mfma_kernel<<<grid, 256, 0, stream>>>(x, Wbf, out);
}